// Round 20
// baseline (49.831 us; speedup 1.0000x reference)
//
#include <hip/hip_runtime.h>
#include <hip/hip_bf16.h>
#include <math.h>

// Problem constants
#define BB   2
#define NN   2048
#define DIMM 512
#define HH   8
#define NC3  1536
#define BN   4096

typedef __attribute__((ext_vector_type(8))) short short8;
typedef __attribute__((ext_vector_type(4))) float f32x4;
typedef unsigned short u16t;

__device__ inline short bfc(float f) {
    __hip_bfloat16 h = __float2bfloat16(f);
    return *reinterpret_cast<short*>(&h);
}
__device__ inline float bf2f(u16t u) {
    return __uint_as_float(((unsigned)u) << 16);
}

// bf16-tile swizzle (64B rows, R15-proven)
#define SWZ(P) ((P) ^ ((((P) >> 7) & 3) << 4))

__device__ inline void gll16(const u16t* gp, void* lp) {
    __builtin_amdgcn_global_load_lds(
        (const __attribute__((address_space(1))) void*)gp,
        (__attribute__((address_space(3))) void*)lp,
        16, 0, 0);
}
__device__ inline void gllf(const float* gp, void* lp) {
    __builtin_amdgcn_global_load_lds(
        (const __attribute__((address_space(1))) void*)gp,
        (__attribute__((address_space(3))) void*)lp,
        16, 0, 0);
}

// ---------------------------------------------------------------------------
// qkv GEMM (NEW: fp32 GLL staging, cvt on LDS->reg; 8x6 per-XCD rectangle):
// QKV[4096x1536](bf16) = x[4096x512](f32) @ w_qkv[1536x512]^T(f32).
// fp32 LDS tiles [128][32], 128B rows, granule swizzle g ^= (r&7):
//   write: linear LDS dest + pre-swizzled global source (GLL rule 21)
//   read : two ds_read_b128 per frag at g0^(r&7), (g0+1)^(r&7), cvt 8x.
// Per-XCD (bid&7) ws: A 8 row-panels (2MB) + B 6 col-panels (1.5MB) < 4MB L2.
// First 64 blocks zero Mm for mpart's atomics.
// ---------------------------------------------------------------------------
__global__ __launch_bounds__(256) void qkvgemm(
    const float* __restrict__ A, const float* __restrict__ Bw,
    u16t* __restrict__ QKV, float* __restrict__ Mm)
{
    __shared__ __align__(16) char smem[65536];   // buf: 32KB = A 16KB + B 16KB

    const int tid  = threadIdx.x;
    const int wave = tid >> 6, lane = tid & 63;
    const int wr = wave >> 1, wc = wave & 1;

    int bid = blockIdx.x;                        // 384 blocks
    if (bid < 64) {
        f32x4 z = (f32x4){0.f, 0.f, 0.f, 0.f};
        ((f32x4*)Mm)[bid * 256 + tid] = z;
    }
    // 8x6 rectangle per XCD: x = bid&7 -> rect (x&3 row-group, x>>2 col-group)
    const int x = bid & 7, k = bid >> 3;         // k in [0,48)
    const int row0 = ((x & 3) * 8 + (k & 7)) * 128;
    const int c0   = ((x >> 2) * 6 + (k >> 3)) * 128;

    // staging: per tile 16 chunks of 1KB (8 rows x 8 granules); wave owns 4.
    // lane l in chunk c: r_loc = c*8 + (l>>3), g_src = (l&7) ^ (l>>3).
    size_t gAo[4], gBo[4];
#pragma unroll
    for (int j = 0; j < 4; ++j) {
        int c = wave * 4 + j;
        int rl = c * 8 + (lane >> 3);
        int gs = (lane & 7) ^ (lane >> 3);
        gAo[j] = (size_t)(row0 + rl) * DIMM + gs * 4;
        gBo[j] = (size_t)(c0   + rl) * DIMM + gs * 4;
    }

    // read addresses: frag (r, kb=(lane>>4)*8): granules g0=kb>>2, g0+1,
    // swizzled with r&7 (= lane&7 since r = 16*i + (lane&15) + 64*w).
    int aA0[4], aA1[4], aB0[4], aB1[4];
    const int g0 = (lane >> 4) * 2;
#pragma unroll
    for (int i = 0; i < 4; ++i) {
        int ra = wr * 64 + i * 16 + (lane & 15);
        aA0[i] = ra * 128 + (((g0    ) ^ (ra & 7)) << 4);
        aA1[i] = ra * 128 + (((g0 + 1) ^ (ra & 7)) << 4);
        int rb2 = wc * 64 + i * 16 + (lane & 15);
        aB0[i] = 16384 + rb2 * 128 + (((g0    ) ^ (rb2 & 7)) << 4);
        aB1[i] = 16384 + rb2 * 128 + (((g0 + 1) ^ (rb2 & 7)) << 4);
    }

#define QSTAGE(BUF, KT) {                                                     \
    char* sb = smem + (BUF) * 32768;                                          \
    _Pragma("unroll")                                                         \
    for (int j = 0; j < 4; ++j) {                                             \
        gllf(A  + gAo[j] + (KT), sb + (wave * 4 + j) * 1024);                 \
        gllf(Bw + gBo[j] + (KT), sb + 16384 + (wave * 4 + j) * 1024);         \
    } }

#define CVT8(FR, LO, HI) {                                                    \
    FR[0] = bfc((LO).x); FR[1] = bfc((LO).y);                                 \
    FR[2] = bfc((LO).z); FR[3] = bfc((LO).w);                                 \
    FR[4] = bfc((HI).x); FR[5] = bfc((HI).y);                                 \
    FR[6] = bfc((HI).z); FR[7] = bfc((HI).w); }

    f32x4 acc[4][4];
#pragma unroll
    for (int i = 0; i < 4; ++i)
#pragma unroll
        for (int j = 0; j < 4; ++j) acc[i][j] = (f32x4){0.f, 0.f, 0.f, 0.f};

    QSTAGE(0, 0);
    for (int t = 0; t < 16; ++t) {
        __syncthreads();                  // drains STAGE(t), fences reads(t-1)
        if (t < 15) QSTAGE((t + 1) & 1, (t + 1) * 32);
        const char* rb = smem + (t & 1) * 32768;
        short8 af[4], bfr[4];
#pragma unroll
        for (int i = 0; i < 4; ++i) {
            float4 lo = *(const float4*)(rb + aA0[i]);
            float4 hi = *(const float4*)(rb + aA1[i]);
            CVT8(af[i], lo, hi);
            float4 lob = *(const float4*)(rb + aB0[i]);
            float4 hib = *(const float4*)(rb + aB1[i]);
            CVT8(bfr[i], lob, hib);
        }
#pragma unroll
        for (int i = 0; i < 4; ++i)
#pragma unroll
            for (int j = 0; j < 4; ++j)
                acc[i][j] = __builtin_amdgcn_mfma_f32_16x16x32_bf16(
                    af[i], bfr[j], acc[i][j], 0, 0, 0);
    }
#undef QSTAGE
#undef CVT8

    // epilogue: bf16 row-major. C/D: col = lane&15, row = (lane>>4)*4 + reg
#pragma unroll
    for (int j = 0; j < 4; ++j) {
        int col = c0 + wc * 64 + j * 16 + (lane & 15);
#pragma unroll
        for (int i = 0; i < 4; ++i) {
#pragma unroll
            for (int r = 0; r < 4; ++r) {
                int row = row0 + wr * 64 + i * 16 + (lane >> 4) * 4 + r;
                QKV[(size_t)row * NC3 + col] = (u16t)bfc(acc[i][j][r]);
            }
        }
    }
}

// ---------------------------------------------------------------------------
// mpart (R19-proven): granule-XOR transposed bf16 tiles + MFMA; atomic
// accumulation into Mm[bh][4096]. grid (16, 16 chunks of 128 rows) x 512.
// ---------------------------------------------------------------------------
#define TST 136

__global__ __launch_bounds__(512) void mpart(
    const u16t* __restrict__ QKV, float* __restrict__ Mm, float* __restrict__ ksump)
{
    __shared__ __align__(16) char sh[34816];
    u16t* ksT = (u16t*)sh;
    u16t* qsT = (u16t*)(sh + 17408);

    const int bh = blockIdx.x, ch = blockIdx.y;
    const int b = bh >> 3, h = bh & 7;
    const int tid = threadIdx.x;
    const u16t* base = QKV + ((size_t)b * NN + ch * 128) * NC3 + h * 64;

    const int k7 = tid & 7;
    const int d0 = k7 * 8;
    const int rr = tid >> 3;

#pragma unroll
    for (int pass = 0; pass < 2; ++pass) {
        int r = pass * 64 + rr;
        const u16t* rowp = base + (size_t)r * NC3 + d0;
        short8 qv = *(const short8*)(rowp);
        short8 kv = *(const short8*)(rowp + 512);
        float e[8]; float s = 0.f;
#pragma unroll
        for (int u = 0; u < 8; ++u) { e[u] = __expf(bf2f((u16t)qv[u])); s += e[u]; }
        s += __shfl_xor(s, 1); s += __shfl_xor(s, 2); s += __shfl_xor(s, 4);
        float inv = 1.0f / s;
        int gx = ((r >> 3) ^ k7) * 8 + (r & 7);
#pragma unroll
        for (int u = 0; u < 8; ++u)
            qsT[(d0 + u) * TST + gx] = (u16t)bfc(e[u] * inv);
#pragma unroll
        for (int u = 0; u < 8; ++u)
            ksT[(d0 + u) * TST + gx] = (u16t)bfc(__expf(bf2f((u16t)kv[u])));
    }
    __syncthreads();

    if (tid < 64) {
        float kss = 0.f;
#pragma unroll
        for (int gg = 0; gg < 16; ++gg) {
            short8 v = *(const short8*)(ksT + tid * TST + gg * 8);
#pragma unroll
            for (int u = 0; u < 8; ++u) kss += bf2f((u16t)v[u]);
        }
        ksump[(bh * 16 + ch) * 64 + tid] = kss;
    }

    const int wave = tid >> 6, lane = tid & 63;
    const int g = wave >> 1, kh = wave & 1;
    const int dl = lane & 15, kq = lane >> 4;
    const int d = g * 16 + dl;

    f32x4 acc[4];
#pragma unroll
    for (int j = 0; j < 4; ++j) acc[j] = (f32x4){0.f, 0.f, 0.f, 0.f};

#pragma unroll
    for (int ks2 = 0; ks2 < 2; ++ks2) {
        int kb = kh * 64 + ks2 * 32 + kq * 8;
        short8 af = *(const short8*)(ksT + d * TST + ((((kb >> 3) ^ (d >> 3))) << 3));
#pragma unroll
        for (int j = 0; j < 4; ++j) {
            int e = j * 16 + dl;
            short8 bfrj = *(const short8*)(qsT + e * TST + ((((kb >> 3) ^ (e >> 3))) << 3));
            acc[j] = __builtin_amdgcn_mfma_f32_16x16x32_bf16(af, bfrj, acc[j], 0, 0, 0);
        }
    }

    float* mm = Mm + (size_t)bh * 4096;
#pragma unroll
    for (int j = 0; j < 4; ++j)
#pragma unroll
        for (int r = 0; r < 4; ++r)
            atomicAdd(&mm[(g * 16 + kq * 4 + r) * 64 + j * 16 + dl], acc[j][r]);
}

// ---------------------------------------------------------------------------
// w2t (R19-proven): grid (16 bh, 16 o-tiles of 32) x 256.
// ---------------------------------------------------------------------------
__global__ __launch_bounds__(256) void w2t(
    const float* __restrict__ Mm, const float* __restrict__ ksump,
    const float* __restrict__ w_out, u16t* __restrict__ W2T)
{
    __shared__ float kst[64];
    __shared__ float Ms[64][68];
    __shared__ float Wt[32][68];

    const int bh = blockIdx.x, ot = blockIdx.y;
    const int b = bh >> 3, h = bh & 7;
    const int tid = threadIdx.x;
    const int d = tid & 63, og = tid >> 6;
    const int ob = ot * 32;

    if (tid < 64) {
        float s = 0.f;
#pragma unroll
        for (int c = 0; c < 16; ++c) s += ksump[(bh * 16 + c) * 64 + tid];
        kst[tid] = s;
    }
#pragma unroll
    for (int it = 0; it < 4; ++it) {
        int idx4 = it * 256 + tid;
        int dd = idx4 >> 4, e4 = idx4 & 15;
        *(float4*)&Ms[dd][e4 * 4] =
            *(const float4*)(Mm + (size_t)bh * 4096 + idx4 * 4);
    }
    {
        int o = tid >> 3, e0 = (tid & 7) * 8;
        *(float4*)&Wt[o][e0] =
            *(const float4*)&w_out[(size_t)(ob + o) * DIMM + h * 64 + e0];
        *(float4*)&Wt[o][e0 + 4] =
            *(const float4*)&w_out[(size_t)(ob + o) * DIMM + h * 64 + e0 + 4];
    }
    __syncthreads();

    float Mreg[64];
#pragma unroll
    for (int e4 = 0; e4 < 16; ++e4) {
        float4 v = *(const float4*)&Ms[d][e4 * 4];
        Mreg[e4 * 4 + 0] = v.x; Mreg[e4 * 4 + 1] = v.y;
        Mreg[e4 * 4 + 2] = v.z; Mreg[e4 * 4 + 3] = v.w;
    }
    float inv = 1.0f / kst[d];

#pragma unroll
    for (int oo = 0; oo < 8; ++oo) {
        int o = og * 8 + oo;
        float a = 0.f;
#pragma unroll
        for (int e4 = 0; e4 < 16; ++e4) {
            float4 wv = *(const float4*)&Wt[o][e4 * 4];
            a += wv.x * Mreg[e4 * 4 + 0] + wv.y * Mreg[e4 * 4 + 1]
               + wv.z * Mreg[e4 * 4 + 2] + wv.w * Mreg[e4 * 4 + 3];
        }
        W2T[((size_t)b * DIMM + ob + o) * DIMM + h * 64 + d] = (u16t)bfc(a * inv);
    }
}

// ---------------------------------------------------------------------------
// out GEMM (R19-proven): Out = V @ W2T^T + bias, row-affine XCD swizzle.
// ---------------------------------------------------------------------------
__global__ __launch_bounds__(256) void outgemm(
    const u16t* __restrict__ Aq, const u16t* __restrict__ W2T,
    const float* __restrict__ bias, float* __restrict__ Out)
{
    __shared__ __align__(16) char smem[24576];

    const int tid  = threadIdx.x;
    const int wave = tid >> 6, lane = tid & 63;
    const int wr = wave >> 1, wc = wave & 1;

    int bid = blockIdx.x;
    const int row0 = ((bid & 7) * 4 + ((bid >> 3) & 3)) * 128;
    const int c0   = (bid >> 5) * 64;
    const u16t* Bp = W2T + (size_t)(row0 >> 11) * (DIMM * DIMM);

    size_t gA[2], gB;
#pragma unroll
    for (int j = 0; j < 2; ++j) {
        int c = wave * 2 + j;
        int gi = SWZ((c * 64 + lane) * 16) >> 4;
        int row = gi >> 2, col = (gi & 3) * 8;
        gA[j] = (size_t)(row0 + row) * NC3 + col;
    }
    {
        int gi = SWZ((wave * 64 + lane) * 16) >> 4;
        int row = gi >> 2, col = (gi & 3) * 8;
        gB = (size_t)(c0 + row) * DIMM + col;
    }

    int rdA[4], rdB[2];
#pragma unroll
    for (int i = 0; i < 4; ++i) {
        int Pa = (wr * 64 + i * 16 + (lane & 15)) * 64 + (lane >> 4) * 16;
        rdA[i] = SWZ(Pa);
    }
#pragma unroll
    for (int j = 0; j < 2; ++j) {
        int Pb = (wc * 32 + j * 16 + (lane & 15)) * 64 + (lane >> 4) * 16;
        rdB[j] = 8192 + SWZ(Pb);
    }

#define OSTAGE(BUF, KT) {                                                     \
    char* sb = smem + (BUF) * 12288;                                          \
    _Pragma("unroll")                                                         \
    for (int j = 0; j < 2; ++j)                                               \
        gll16(Aq + gA[j] + (KT), sb + (wave * 2 + j) * 1024);                 \
    gll16(Bp + gB + (KT), sb + 8192 + wave * 1024);                           \
    }

    f32x4 acc[4][2];
#pragma unroll
    for (int i = 0; i < 4; ++i)
#pragma unroll
        for (int j = 0; j < 2; ++j) acc[i][j] = (f32x4){0.f, 0.f, 0.f, 0.f};

    OSTAGE(0, 0);
    for (int t = 0; t < 16; ++t) {
        __syncthreads();
        if (t < 15) OSTAGE((t + 1) & 1, (t + 1) * 32);
        const char* rb = smem + (t & 1) * 12288;
        short8 af[4], bfr[2];
#pragma unroll
        for (int i = 0; i < 4; ++i) af[i]  = *(const short8*)(rb + rdA[i]);
#pragma unroll
        for (int j = 0; j < 2; ++j) bfr[j] = *(const short8*)(rb + rdB[j]);
#pragma unroll
        for (int i = 0; i < 4; ++i)
#pragma unroll
            for (int j = 0; j < 2; ++j)
                acc[i][j] = __builtin_amdgcn_mfma_f32_16x16x32_bf16(
                    af[i], bfr[j], acc[i][j], 0, 0, 0);
    }
#undef OSTAGE

#pragma unroll
    for (int j = 0; j < 2; ++j) {
        int col = c0 + wc * 32 + j * 16 + (lane & 15);
        float bb = bias[col];
#pragma unroll
        for (int i = 0; i < 4; ++i) {
#pragma unroll
            for (int r = 0; r < 4; ++r) {
                int row = row0 + wr * 64 + i * 16 + (lane >> 4) * 4 + r;
                Out[(size_t)row * DIMM + col] = acc[i][j][r] + bb;
            }
        }
    }
}

// ---------------------------------------------------------------------------
extern "C" void kernel_launch(void* const* d_in, const int* in_sizes, int n_in,
                              void* d_out, int out_size, void* d_ws, size_t ws_size,
                              hipStream_t stream)
{
    const float* x     = (const float*)d_in[0];
    const float* w_qkv = (const float*)d_in[1];
    const float* w_out = (const float*)d_in[2];
    const float* b_out = (const float*)d_in[3];
    float* out = (float*)d_out;

    char* w = (char*)d_ws;
    u16t*  QKV  = (u16t*) (w);              // 12,582,912 B
    float* Mm   = (float*)(w + 12582912);   //    262,144 B
    float* ksum = (float*)(w + 12845056);   //     65,536 B
    u16t*  W2T  = (u16t*) (w + 12910592);   //  1,048,576 B  (end ~14 MB)

    // 1) qkv projection (fp32 GLL staging + cvt-on-read, 8x6 XCD rect);
    //    zeroes Mm. No cvt kernel anymore.
    qkvgemm<<<dim3(384), 256, 0, stream>>>(x, w_qkv, QKV, Mm);

    // 2) M via MFMA + atomic fp32 accumulation into Mm
    mpart<<<dim3(16, 16), 512, 0, stream>>>(QKV, Mm, ksum);

    // 3) fold M into w_out -> W2T (256 blocks)
    w2t<<<dim3(16, 16), 256, 0, stream>>>(Mm, ksum, w_out, W2T);

    // 4) out = V @ W2T^T + bias
    outgemm<<<dim3(256), 256, 0, stream>>>(QKV + 1024, W2T, b_out, out);
}

// Round 21
// 47.936 us; speedup vs baseline: 1.0395x; 1.0395x over previous
//
#include <hip/hip_runtime.h>
#include <hip/hip_bf16.h>
#include <math.h>

// Problem constants
#define BB   2
#define NN   2048
#define DIMM 512
#define HH   8
#define NC3  1536
#define BN   4096

typedef __attribute__((ext_vector_type(8))) short short8;
typedef __attribute__((ext_vector_type(4))) float f32x4;
typedef unsigned short u16t;

__device__ inline short bfc(float f) {
    __hip_bfloat16 h = __float2bfloat16(f);
    return *reinterpret_cast<short*>(&h);
}
__device__ inline float bf2f(u16t u) {
    return __uint_as_float(((unsigned)u) << 16);
}

// XOR-swizzle of 16B granules within [rows x 64B] LDS tiles (involution).
#define SWZ(P) ((P) ^ ((((P) >> 7) & 3) << 4))

__device__ inline void gll16(const u16t* gp, void* lp) {
    __builtin_amdgcn_global_load_lds(
        (const __attribute__((address_space(1))) void*)gp,
        (__attribute__((address_space(3))) void*)lp,
        16, 0, 0);
}

// ---------------------------------------------------------------------------
// fp32 -> bf16 (proven): x = 524288 float4, w_qkv = 196608 float4.
// ---------------------------------------------------------------------------
__global__ __launch_bounds__(256) void cvt_bf16(
    const float* __restrict__ x, const float* __restrict__ wq,
    u16t* __restrict__ xb, u16t* __restrict__ wqb)
{
    int t = blockIdx.x * 256 + threadIdx.x;
    const float4* src; ushort4* dst; int i;
    if (t < 524288) { src = (const float4*)x;  dst = (ushort4*)xb;  i = t; }
    else            { src = (const float4*)wq; dst = (ushort4*)wqb; i = t - 524288; }
    float4 v = src[i];
    ushort4 u;
    u.x = (u16t)bfc(v.x); u.y = (u16t)bfc(v.y);
    u.z = (u16t)bfc(v.z); u.w = (u16t)bfc(v.w);
    dst[i] = u;
}

// ---------------------------------------------------------------------------
// qkv GEMM (proven): GLL bf16, row-affine XCD swizzle.
// First 64 blocks also zero Mm (for mpart's atomic accumulation).
// ---------------------------------------------------------------------------
__global__ __launch_bounds__(256) void qkvgemm(
    const u16t* __restrict__ A, const u16t* __restrict__ Bw,
    u16t* __restrict__ QKV, float* __restrict__ Mm)
{
    __shared__ __align__(16) char smem[32768];

    const int tid  = threadIdx.x;
    const int wave = tid >> 6, lane = tid & 63;
    const int wr = wave >> 1, wc = wave & 1;

    int bid = blockIdx.x;
    if (bid < 64) {
        f32x4 z = (f32x4){0.f, 0.f, 0.f, 0.f};
        ((f32x4*)Mm)[bid * 256 + tid] = z;      // 64*256 float4 = 65536 floats
    }
    const int row0 = ((bid & 7) * 4 + ((bid >> 3) & 3)) * 128;
    const int c0   = (bid >> 5) * 128;

    size_t gA[2], gB[2];
#pragma unroll
    for (int j = 0; j < 2; ++j) {
        int c = wave * 2 + j;
        int X = (c * 64 + lane) * 16;
        int gi = SWZ(X) >> 4;
        int row = gi >> 2, col = (gi & 3) * 8;
        gA[j] = (size_t)(row0 + row) * DIMM + col;
        gB[j] = (size_t)(c0   + row) * DIMM + col;
    }

    int rdA[4], rdB[4];
#pragma unroll
    for (int i = 0; i < 4; ++i) {
        int Pa = (wr * 64 + i * 16 + (lane & 15)) * 64 + (lane >> 4) * 16;
        rdA[i] = SWZ(Pa);
        int Pb = (wc * 64 + i * 16 + (lane & 15)) * 64 + (lane >> 4) * 16;
        rdB[i] = 8192 + SWZ(Pb);
    }

#define QSTAGE(BUF, KT) {                                                     \
    char* sb = smem + (BUF) * 16384;                                          \
    _Pragma("unroll")                                                         \
    for (int j = 0; j < 2; ++j) {                                             \
        gll16(A  + gA[j] + (KT), sb + (wave * 2 + j) * 1024);                 \
        gll16(Bw + gB[j] + (KT), sb + 8192 + (wave * 2 + j) * 1024);          \
    } }

    f32x4 acc[4][4];
#pragma unroll
    for (int i = 0; i < 4; ++i)
#pragma unroll
        for (int j = 0; j < 4; ++j) acc[i][j] = (f32x4){0.f, 0.f, 0.f, 0.f};

    QSTAGE(0, 0);
    for (int t = 0; t < 16; ++t) {
        __syncthreads();
        if (t < 15) QSTAGE((t + 1) & 1, (t + 1) * 32);
        const char* rb = smem + (t & 1) * 16384;
        short8 af[4], bfr[4];
#pragma unroll
        for (int i = 0; i < 4; ++i) {
            af[i]  = *(const short8*)(rb + rdA[i]);
            bfr[i] = *(const short8*)(rb + rdB[i]);
        }
#pragma unroll
        for (int i = 0; i < 4; ++i)
#pragma unroll
            for (int j = 0; j < 4; ++j)
                acc[i][j] = __builtin_amdgcn_mfma_f32_16x16x32_bf16(
                    af[i], bfr[j], acc[i][j], 0, 0, 0);
    }
#undef QSTAGE

#pragma unroll
    for (int j = 0; j < 4; ++j) {
        int col = c0 + wc * 64 + j * 16 + (lane & 15);
#pragma unroll
        for (int i = 0; i < 4; ++i) {
#pragma unroll
            for (int r = 0; r < 4; ++r) {
                int row = row0 + wr * 64 + i * 16 + (lane >> 4) * 4 + r;
                QKV[(size_t)row * NC3 + col] = (u16t)bfc(acc[i][j][r]);
            }
        }
    }
}

// ---------------------------------------------------------------------------
// mpart (proven): granule-XOR transposed bf16 tiles + MFMA; phase 3
// ATOMIC-accumulates into Mm[bh][4096]. grid (16, 16 chunks of 128) x 512.
// ---------------------------------------------------------------------------
#define TST 136

__global__ __launch_bounds__(512) void mpart(
    const u16t* __restrict__ QKV, float* __restrict__ Mm, float* __restrict__ ksump)
{
    __shared__ __align__(16) char sh[34816];
    u16t* ksT = (u16t*)sh;
    u16t* qsT = (u16t*)(sh + 17408);

    const int bh = blockIdx.x, ch = blockIdx.y;
    const int b = bh >> 3, h = bh & 7;
    const int tid = threadIdx.x;
    const u16t* base = QKV + ((size_t)b * NN + ch * 128) * NC3 + h * 64;

    const int k7 = tid & 7;
    const int d0 = k7 * 8;
    const int rr = tid >> 3;

#pragma unroll
    for (int pass = 0; pass < 2; ++pass) {
        int r = pass * 64 + rr;
        const u16t* rowp = base + (size_t)r * NC3 + d0;
        short8 qv = *(const short8*)(rowp);
        short8 kv = *(const short8*)(rowp + 512);
        float e[8]; float s = 0.f;
#pragma unroll
        for (int u = 0; u < 8; ++u) { e[u] = __expf(bf2f((u16t)qv[u])); s += e[u]; }
        s += __shfl_xor(s, 1); s += __shfl_xor(s, 2); s += __shfl_xor(s, 4);
        float inv = 1.0f / s;
        int gx = ((r >> 3) ^ k7) * 8 + (r & 7);
#pragma unroll
        for (int u = 0; u < 8; ++u)
            qsT[(d0 + u) * TST + gx] = (u16t)bfc(e[u] * inv);
#pragma unroll
        for (int u = 0; u < 8; ++u)
            ksT[(d0 + u) * TST + gx] = (u16t)bfc(__expf(bf2f((u16t)kv[u])));
    }
    __syncthreads();

    if (tid < 64) {
        float kss = 0.f;
#pragma unroll
        for (int gg = 0; gg < 16; ++gg) {
            short8 v = *(const short8*)(ksT + tid * TST + gg * 8);
#pragma unroll
            for (int u = 0; u < 8; ++u) kss += bf2f((u16t)v[u]);
        }
        ksump[(bh * 16 + ch) * 64 + tid] = kss;
    }

    const int wave = tid >> 6, lane = tid & 63;
    const int g = wave >> 1, kh = wave & 1;
    const int dl = lane & 15, kq = lane >> 4;
    const int d = g * 16 + dl;

    f32x4 acc[4];
#pragma unroll
    for (int j = 0; j < 4; ++j) acc[j] = (f32x4){0.f, 0.f, 0.f, 0.f};

#pragma unroll
    for (int ks2 = 0; ks2 < 2; ++ks2) {
        int kb = kh * 64 + ks2 * 32 + kq * 8;
        short8 af = *(const short8*)(ksT + d * TST + ((((kb >> 3) ^ (d >> 3))) << 3));
#pragma unroll
        for (int j = 0; j < 4; ++j) {
            int e = j * 16 + dl;
            short8 bfrj = *(const short8*)(qsT + e * TST + ((((kb >> 3) ^ (e >> 3))) << 3));
            acc[j] = __builtin_amdgcn_mfma_f32_16x16x32_bf16(af, bfrj, acc[j], 0, 0, 0);
        }
    }

    // phase 3: atomic accumulate (fire-and-forget native f32 add)
    float* mm = Mm + (size_t)bh * 4096;
#pragma unroll
    for (int j = 0; j < 4; ++j)
#pragma unroll
        for (int r = 0; r < 4; ++r)
            atomicAdd(&mm[(g * 16 + kq * 4 + r) * 64 + j * 16 + dl], acc[j][r]);
}

// ---------------------------------------------------------------------------
// w2t (proven, 256 blocks): grid (16 bh, 16 o-tiles of 32) x 256.
//   W2T[b][o][h*64+d] = (1/kst[d]) * sum_e M[bh][d][e] * w_out[o][h*64+e]
// ---------------------------------------------------------------------------
__global__ __launch_bounds__(256) void w2t(
    const float* __restrict__ Mm, const float* __restrict__ ksump,
    const float* __restrict__ w_out, u16t* __restrict__ W2T)
{
    __shared__ float kst[64];
    __shared__ float Ms[64][68];
    __shared__ float Wt[32][68];

    const int bh = blockIdx.x, ot = blockIdx.y;
    const int b = bh >> 3, h = bh & 7;
    const int tid = threadIdx.x;
    const int d = tid & 63, og = tid >> 6;   // og in [0,4)
    const int ob = ot * 32;

    if (tid < 64) {
        float s = 0.f;
#pragma unroll
        for (int c = 0; c < 16; ++c) s += ksump[(bh * 16 + c) * 64 + tid];
        kst[tid] = s;
    }
#pragma unroll
    for (int it = 0; it < 4; ++it) {
        int idx4 = it * 256 + tid;               // 0..1023
        int dd = idx4 >> 4, e4 = idx4 & 15;
        *(float4*)&Ms[dd][e4 * 4] =
            *(const float4*)(Mm + (size_t)bh * 4096 + idx4 * 4);
    }
    {
        int o = tid >> 3, e0 = (tid & 7) * 8;    // o 0..31
        *(float4*)&Wt[o][e0] =
            *(const float4*)&w_out[(size_t)(ob + o) * DIMM + h * 64 + e0];
        *(float4*)&Wt[o][e0 + 4] =
            *(const float4*)&w_out[(size_t)(ob + o) * DIMM + h * 64 + e0 + 4];
    }
    __syncthreads();

    float Mreg[64];
#pragma unroll
    for (int e4 = 0; e4 < 16; ++e4) {
        float4 v = *(const float4*)&Ms[d][e4 * 4];
        Mreg[e4 * 4 + 0] = v.x; Mreg[e4 * 4 + 1] = v.y;
        Mreg[e4 * 4 + 2] = v.z; Mreg[e4 * 4 + 3] = v.w;
    }
    float inv = 1.0f / kst[d];

#pragma unroll
    for (int oo = 0; oo < 8; ++oo) {
        int o = og * 8 + oo;
        float a = 0.f;
#pragma unroll
        for (int e4 = 0; e4 < 16; ++e4) {
            float4 wv = *(const float4*)&Wt[o][e4 * 4];
            a += wv.x * Mreg[e4 * 4 + 0] + wv.y * Mreg[e4 * 4 + 1]
               + wv.z * Mreg[e4 * 4 + 2] + wv.w * Mreg[e4 * 4 + 3];
        }
        W2T[((size_t)b * DIMM + ob + o) * DIMM + h * 64 + d] = (u16t)bfc(a * inv);
    }
}

// ---------------------------------------------------------------------------
// out GEMM (proven): Out = V @ W2T^T + bias, row-affine XCD swizzle.
// ---------------------------------------------------------------------------
__global__ __launch_bounds__(256) void outgemm(
    const u16t* __restrict__ Aq, const u16t* __restrict__ W2T,
    const float* __restrict__ bias, float* __restrict__ Out)
{
    __shared__ __align__(16) char smem[24576];

    const int tid  = threadIdx.x;
    const int wave = tid >> 6, lane = tid & 63;
    const int wr = wave >> 1, wc = wave & 1;

    int bid = blockIdx.x;
    const int row0 = ((bid & 7) * 4 + ((bid >> 3) & 3)) * 128;
    const int c0   = (bid >> 5) * 64;
    const u16t* Bp = W2T + (size_t)(row0 >> 11) * (DIMM * DIMM);

    size_t gA[2], gB;
#pragma unroll
    for (int j = 0; j < 2; ++j) {
        int c = wave * 2 + j;
        int gi = SWZ((c * 64 + lane) * 16) >> 4;
        int row = gi >> 2, col = (gi & 3) * 8;
        gA[j] = (size_t)(row0 + row) * NC3 + col;
    }
    {
        int gi = SWZ((wave * 64 + lane) * 16) >> 4;
        int row = gi >> 2, col = (gi & 3) * 8;
        gB = (size_t)(c0 + row) * DIMM + col;
    }

    int rdA[4], rdB[2];
#pragma unroll
    for (int i = 0; i < 4; ++i) {
        int Pa = (wr * 64 + i * 16 + (lane & 15)) * 64 + (lane >> 4) * 16;
        rdA[i] = SWZ(Pa);
    }
#pragma unroll
    for (int j = 0; j < 2; ++j) {
        int Pb = (wc * 32 + j * 16 + (lane & 15)) * 64 + (lane >> 4) * 16;
        rdB[j] = 8192 + SWZ(Pb);
    }

#define OSTAGE(BUF, KT) {                                                     \
    char* sb = smem + (BUF) * 12288;                                          \
    _Pragma("unroll")                                                         \
    for (int j = 0; j < 2; ++j)                                               \
        gll16(Aq + gA[j] + (KT), sb + (wave * 2 + j) * 1024);                 \
    gll16(Bp + gB + (KT), sb + 8192 + wave * 1024);                           \
    }

    f32x4 acc[4][2];
#pragma unroll
    for (int i = 0; i < 4; ++i)
#pragma unroll
        for (int j = 0; j < 2; ++j) acc[i][j] = (f32x4){0.f, 0.f, 0.f, 0.f};

    OSTAGE(0, 0);
    for (int t = 0; t < 16; ++t) {
        __syncthreads();
        if (t < 15) OSTAGE((t + 1) & 1, (t + 1) * 32);
        const char* rb = smem + (t & 1) * 12288;
        short8 af[4], bfr[2];
#pragma unroll
        for (int i = 0; i < 4; ++i) af[i]  = *(const short8*)(rb + rdA[i]);
#pragma unroll
        for (int j = 0; j < 2; ++j) bfr[j] = *(const short8*)(rb + rdB[j]);
#pragma unroll
        for (int i = 0; i < 4; ++i)
#pragma unroll
            for (int j = 0; j < 2; ++j)
                acc[i][j] = __builtin_amdgcn_mfma_f32_16x16x32_bf16(
                    af[i], bfr[j], acc[i][j], 0, 0, 0);
    }
#undef OSTAGE

#pragma unroll
    for (int j = 0; j < 2; ++j) {
        int col = c0 + wc * 32 + j * 16 + (lane & 15);
        float bb = bias[col];
#pragma unroll
        for (int i = 0; i < 4; ++i) {
#pragma unroll
            for (int r = 0; r < 4; ++r) {
                int row = row0 + wr * 64 + i * 16 + (lane >> 4) * 4 + r;
                Out[(size_t)row * DIMM + col] = acc[i][j][r] + bb;
            }
        }
    }
}

// ---------------------------------------------------------------------------
extern "C" void kernel_launch(void* const* d_in, const int* in_sizes, int n_in,
                              void* d_out, int out_size, void* d_ws, size_t ws_size,
                              hipStream_t stream)
{
    const float* x     = (const float*)d_in[0];
    const float* w_qkv = (const float*)d_in[1];
    const float* w_out = (const float*)d_in[2];
    const float* b_out = (const float*)d_in[3];
    float* out = (float*)d_out;

    char* w = (char*)d_ws;
    u16t*  xb   = (u16t*) (w);              //  4,194,304 B
    u16t*  wqb  = (u16t*) (w + 4194304);    //  1,572,864 B
    u16t*  QKV  = (u16t*) (w + 5767168);    // 12,582,912 B
    float* Mm   = (float*)(w + 18350080);   //    262,144 B
    float* ksum = (float*)(w + 18612224);   //     65,536 B
    u16t*  W2T  = (u16t*) (w + 18677760);   //  1,048,576 B  (end ~19.7 MB)

    // 1) fp32 -> bf16 for GEMM inputs
    cvt_bf16<<<dim3(2816), 256, 0, stream>>>(x, w_qkv, xb, wqb);

    // 2) qkv projection (GLL bf16, row-affine XCD swizzle); zeroes Mm
    qkvgemm<<<dim3(384), 256, 0, stream>>>(xb, wqb, QKV, Mm);

    // 3) M via MFMA + atomic fp32 accumulation into Mm (no reduce pass)
    mpart<<<dim3(16, 16), 512, 0, stream>>>(QKV, Mm, ksum);

    // 4) fold M into w_out -> W2T (256 blocks)
    w2t<<<dim3(16, 16), 256, 0, stream>>>(Mm, ksum, w_out, W2T);

    // 5) out = V @ W2T^T + bias
    outgemm<<<dim3(256), 256, 0, stream>>>(QKV + 1024, W2T, b_out, out);
}